// Round 10
// baseline (265.039 us; speedup 1.0000x reference)
//
#include <hip/hip_runtime.h>
#include <hip/hip_bf16.h>

// GIN: 3x [agg = segment_sum(h[src], dst); r = h + agg; h = relu(r@Wa+ba)@Wb+bb]
// then mean over nodes @ Wout + bout -> [1,16]
//
// R10: dual-row INTERLEAVED gather: each thread owns rows m0+g and m0+8+g;
// their edge streams are walked jointly (8+8 independent 16B row loads in
// flight vs R9's sequential 8) -> serialized latency units per thread ~halved.
// Everything else identical to R9 (sort chain, single-barrier MFMA MLP, pool).

#define NNODES 50000
#define NEDGES 800000
#define DDIM   64
#define DOUT   16

#define CHUNK  4096
#define NB1    196           // ceil(800000/4096)
#define NBUCK  196           // ceil(50000/256), bucket = dst>>8
#define NBCVT  6250          // cvt blocks: 1.6M float2 / 256
#define NB64   782           // ceil(50000/64), fused-layer blocks

typedef unsigned int uint;
typedef unsigned short ushort;
typedef __attribute__((ext_vector_type(8))) short bf16x8;
typedef __attribute__((ext_vector_type(4))) float f32x4;

#define LSTR 72   // LDS row stride in ushorts (144B rows, 16B-aligned)

// fp32 -> bf16 RNE (bit trick)
static __device__ __forceinline__ uint f2bf(float f) {
    uint u = __float_as_uint(f);
    return (u + 0x7fffu + ((u >> 16) & 1u)) >> 16;
}
static __device__ __forceinline__ float bf_lo(uint u) { return __uint_as_float(u << 16); }
static __device__ __forceinline__ float bf_hi(uint u) { return __uint_as_float(u & 0xffff0000u); }

// ---------------- S1: pack keys + per-block bucket hist; tail blocks do cvt ----------------

__global__ __launch_bounds__(256) void sort_hist_cvt_kernel(const int* __restrict__ src,
                                                            const int* __restrict__ dst,
                                                            uint* __restrict__ key,
                                                            int* __restrict__ gh,
                                                            const float2* __restrict__ fin,
                                                            uint* __restrict__ hb, int n) {
    __shared__ int h[NBUCK];
    int blk = blockIdx.x;
    if (blk >= NB1) {
        int i = (blk - NB1) * 256 + threadIdx.x;
        if (i < NNODES * 32) {
            float2 v = fin[i];
            hb[i] = f2bf(v.x) | (f2bf(v.y) << 16);
        }
        return;
    }
    for (int i = threadIdx.x; i < NBUCK; i += 256) h[i] = 0;
    __syncthreads();
    int base = blk * CHUNK;
    int end = base + CHUNK < n ? base + CHUNK : n;
    for (int i = base + threadIdx.x; i < end; i += 256) {
        int d = dst[i];
        key[i] = ((uint)d << 16) | (uint)src[i];
        atomicAdd(&h[d >> 8], 1);
    }
    __syncthreads();
    for (int i = threadIdx.x; i < NBUCK; i += 256) gh[blk * NBUCK + i] = h[i];
}

// ---------------- S2a: per-bucket scan over the 196 chunk counts ----------------

__global__ __launch_bounds__(256) void sort_offsets_a_kernel(const int* __restrict__ gh,
                                                             int* __restrict__ offraw,
                                                             int* __restrict__ tot) {
    __shared__ int s[256];
    int b = blockIdx.x;
    int i = threadIdx.x;
    int v = (i < NB1) ? gh[i * NBUCK + b] : 0;
    s[i] = v;
    __syncthreads();
    for (int off = 1; off < 256; off <<= 1) {
        int add = (i >= off) ? s[i - off] : 0;
        __syncthreads();
        s[i] += add;
        __syncthreads();
    }
    if (i < NB1) offraw[i * NBUCK + b] = s[i] - v;   // exclusive within bucket
    if (i == 255) tot[b] = s[255];
}

// ---------------- S2b: scan bucket totals -> bucket bases ----------------

__global__ __launch_bounds__(256) void sort_offsets_b_kernel(const int* __restrict__ tot,
                                                             int* __restrict__ bbase) {
    __shared__ int s[256];
    int i = threadIdx.x;
    int v = (i < NBUCK) ? tot[i] : 0;
    s[i] = v;
    __syncthreads();
    for (int off = 1; off < 256; off <<= 1) {
        int add = (i >= off) ? s[i - off] : 0;
        __syncthreads();
        s[i] += add;
        __syncthreads();
    }
    if (i < NBUCK) bbase[i] = s[i] - v;   // exclusive
    if (i == 0) bbase[NBUCK] = NEDGES;
}

// ---------------- S3: partition into coarse buckets (block-private runs) ----------------

__global__ __launch_bounds__(256) void sort_scatter1_kernel(const uint* __restrict__ key,
                                                            const int* __restrict__ offraw,
                                                            const int* __restrict__ bbase,
                                                            uint* __restrict__ out, int n) {
    __shared__ int cur[NBUCK];
    int blk = blockIdx.x;
    for (int i = threadIdx.x; i < NBUCK; i += 256)
        cur[i] = bbase[i] + offraw[blk * NBUCK + i];
    __syncthreads();
    int base = blk * CHUNK;
    int end = base + CHUNK < n ? base + CHUNK : n;
    for (int i = base + threadIdx.x; i < end; i += 256) {
        uint k = key[i];
        int pos = atomicAdd(&cur[k >> 24], 1);   // k>>24 == dst>>8
        out[pos] = k;
    }
}

// ---------------- S4: per-bucket counting sort by dst&255; emits rowptr ----------------

__global__ __launch_bounds__(256) void sort_bucket_kernel(const uint* __restrict__ in,
                                                          const int* __restrict__ bbase,
                                                          int* __restrict__ rowptr,
                                                          uint* __restrict__ out) {
    __shared__ int h[256];
    __shared__ int cur[256];
    int b = blockIdx.x;
    int t = threadIdx.x;
    int lo = bbase[b], hi = bbase[b + 1];
    h[t] = 0;
    __syncthreads();
    for (int i = lo + t; i < hi; i += 256)
        atomicAdd(&h[(in[i] >> 16) & 255], 1);
    __syncthreads();
    if (t == 0) {
        int run = lo;
        for (int i = 0; i < 256; i++) { cur[i] = run; run += h[i]; }
    }
    __syncthreads();
    int node = (b << 8) + t;
    if (node < NNODES) rowptr[node] = cur[t];
    if (b == NBUCK - 1 && t == 0) rowptr[NNODES] = NEDGES;
    __syncthreads();   // rowptr reads of cur[] before scatter mutates it
    for (int i = lo + t; i < hi; i += 256) {
        uint k = in[i];
        int pos = atomicAdd(&cur[(k >> 16) & 255], 1);
        out[pos] = k;
    }
}

// ---------------- fused GIN layer: gather-agg + relu(X@Wa+ba)@Wb+bb ----------------
// 64 nodes/block, 4 waves; wave w owns rows 16w..16w+15 end-to-end.
// Gather: group g (8 lanes, p=lane&7, uint4 = dims 8p..8p+7) owns rows
// m0+g (A) and m0+8+g (B); A/B edge streams interleaved -> 16 row loads
// in flight. fp32 register accumulation, one LDS flush per row.

__global__ __launch_bounds__(256) void gin_layer_kernel(const uint4* __restrict__ h128,
                                                        const int* __restrict__ rowptr,
                                                        const uint* __restrict__ skey,
                                                        const float* __restrict__ Wa,
                                                        const float* __restrict__ ba,
                                                        const float* __restrict__ Wb,
                                                        const float* __restrict__ bb,
                                                        uint4* __restrict__ out128, int n) {
    __shared__ ushort sW1[64 * LSTR];   // Wa^T: [n][k]
    __shared__ ushort sW2[64 * LSTR];   // Wb^T: [n][k]
    __shared__ ushort sX[64 * LSTR];    // r tile -> hidden tile -> output staging
    __shared__ float sba[64], sbb[64];

    int t = threadIdx.x;
    for (int i = t; i < 4096; i += 256) {
        int k = i >> 6, nn = i & 63;
        sW1[nn * LSTR + k] = (ushort)f2bf(Wa[i]);
        sW2[nn * LSTR + k] = (ushort)f2bf(Wb[i]);
    }
    if (t < 64) { sba[t] = ba[t]; sbb[t] = bb[t]; }
    __syncthreads();   // the only barrier: weights visible to all waves

    int node0 = blockIdx.x * 64;
    int lane = t & 63;
    int w = t >> 6;
    int m0 = w * 16;
    int g = lane >> 3;       // group 0..7
    int p = lane & 7;        // uint4 index (dims 8p..8p+7)

    int rowA = m0 + g, rowB = m0 + 8 + g;
    int vA = node0 + rowA, vB = node0 + rowB;
    bool okA = vA < n, okB = vB < n;

    float aA0 = 0.f, aA1 = 0.f, aA2 = 0.f, aA3 = 0.f, aA4 = 0.f, aA5 = 0.f, aA6 = 0.f, aA7 = 0.f;
    float aB0 = 0.f, aB1 = 0.f, aB2 = 0.f, aB3 = 0.f, aB4 = 0.f, aB5 = 0.f, aB6 = 0.f, aB7 = 0.f;
    int eA = 0, eA1v = 0, eB = 0, eB1v = 0;

    if (okA) { eA = rowptr[vA]; eA1v = rowptr[vA + 1]; }
    if (okB) { eB = rowptr[vB]; eB1v = rowptr[vB + 1]; }
    if (okA) {
        uint4 su = h128[(size_t)vA * 8 + p];
        aA0 = bf_lo(su.x); aA1 = bf_hi(su.x); aA2 = bf_lo(su.y); aA3 = bf_hi(su.y);
        aA4 = bf_lo(su.z); aA5 = bf_hi(su.z); aA6 = bf_lo(su.w); aA7 = bf_hi(su.w);
    }
    if (okB) {
        uint4 su = h128[(size_t)vB * 8 + p];
        aB0 = bf_lo(su.x); aB1 = bf_hi(su.x); aB2 = bf_lo(su.y); aB3 = bf_hi(su.y);
        aB4 = bf_lo(su.z); aB5 = bf_hi(su.z); aB6 = bf_lo(su.w); aB7 = bf_hi(su.w);
    }

    // joint loop: 8 A-loads + 8 B-loads in flight
    while (eA + 8 <= eA1v && eB + 8 <= eB1v) {
        uint kA0 = skey[eA + 0], kA1 = skey[eA + 1], kA2 = skey[eA + 2], kA3 = skey[eA + 3];
        uint kA4 = skey[eA + 4], kA5 = skey[eA + 5], kA6 = skey[eA + 6], kA7 = skey[eA + 7];
        uint kB0 = skey[eB + 0], kB1 = skey[eB + 1], kB2 = skey[eB + 2], kB3 = skey[eB + 3];
        uint kB4 = skey[eB + 4], kB5 = skey[eB + 5], kB6 = skey[eB + 6], kB7 = skey[eB + 7];
        uint4 x0 = h128[(size_t)(kA0 & 0xffffu) * 8 + p];
        uint4 x1 = h128[(size_t)(kA1 & 0xffffu) * 8 + p];
        uint4 x2 = h128[(size_t)(kA2 & 0xffffu) * 8 + p];
        uint4 x3 = h128[(size_t)(kA3 & 0xffffu) * 8 + p];
        uint4 x4 = h128[(size_t)(kA4 & 0xffffu) * 8 + p];
        uint4 x5 = h128[(size_t)(kA5 & 0xffffu) * 8 + p];
        uint4 x6 = h128[(size_t)(kA6 & 0xffffu) * 8 + p];
        uint4 x7 = h128[(size_t)(kA7 & 0xffffu) * 8 + p];
        uint4 y0 = h128[(size_t)(kB0 & 0xffffu) * 8 + p];
        uint4 y1 = h128[(size_t)(kB1 & 0xffffu) * 8 + p];
        uint4 y2 = h128[(size_t)(kB2 & 0xffffu) * 8 + p];
        uint4 y3 = h128[(size_t)(kB3 & 0xffffu) * 8 + p];
        uint4 y4 = h128[(size_t)(kB4 & 0xffffu) * 8 + p];
        uint4 y5 = h128[(size_t)(kB5 & 0xffffu) * 8 + p];
        uint4 y6 = h128[(size_t)(kB6 & 0xffffu) * 8 + p];
        uint4 y7 = h128[(size_t)(kB7 & 0xffffu) * 8 + p];
        aA0 += bf_lo(x0.x); aA1 += bf_hi(x0.x); aA2 += bf_lo(x0.y); aA3 += bf_hi(x0.y);
        aA4 += bf_lo(x0.z); aA5 += bf_hi(x0.z); aA6 += bf_lo(x0.w); aA7 += bf_hi(x0.w);
        aA0 += bf_lo(x1.x); aA1 += bf_hi(x1.x); aA2 += bf_lo(x1.y); aA3 += bf_hi(x1.y);
        aA4 += bf_lo(x1.z); aA5 += bf_hi(x1.z); aA6 += bf_lo(x1.w); aA7 += bf_hi(x1.w);
        aA0 += bf_lo(x2.x); aA1 += bf_hi(x2.x); aA2 += bf_lo(x2.y); aA3 += bf_hi(x2.y);
        aA4 += bf_lo(x2.z); aA5 += bf_hi(x2.z); aA6 += bf_lo(x2.w); aA7 += bf_hi(x2.w);
        aA0 += bf_lo(x3.x); aA1 += bf_hi(x3.x); aA2 += bf_lo(x3.y); aA3 += bf_hi(x3.y);
        aA4 += bf_lo(x3.z); aA5 += bf_hi(x3.z); aA6 += bf_lo(x3.w); aA7 += bf_hi(x3.w);
        aA0 += bf_lo(x4.x); aA1 += bf_hi(x4.x); aA2 += bf_lo(x4.y); aA3 += bf_hi(x4.y);
        aA4 += bf_lo(x4.z); aA5 += bf_hi(x4.z); aA6 += bf_lo(x4.w); aA7 += bf_hi(x4.w);
        aA0 += bf_lo(x5.x); aA1 += bf_hi(x5.x); aA2 += bf_lo(x5.y); aA3 += bf_hi(x5.y);
        aA4 += bf_lo(x5.z); aA5 += bf_hi(x5.z); aA6 += bf_lo(x5.w); aA7 += bf_hi(x5.w);
        aA0 += bf_lo(x6.x); aA1 += bf_hi(x6.x); aA2 += bf_lo(x6.y); aA3 += bf_hi(x6.y);
        aA4 += bf_lo(x6.z); aA5 += bf_hi(x6.z); aA6 += bf_lo(x6.w); aA7 += bf_hi(x6.w);
        aA0 += bf_lo(x7.x); aA1 += bf_hi(x7.x); aA2 += bf_lo(x7.y); aA3 += bf_hi(x7.y);
        aA4 += bf_lo(x7.z); aA5 += bf_hi(x7.z); aA6 += bf_lo(x7.w); aA7 += bf_hi(x7.w);
        aB0 += bf_lo(y0.x); aB1 += bf_hi(y0.x); aB2 += bf_lo(y0.y); aB3 += bf_hi(y0.y);
        aB4 += bf_lo(y0.z); aB5 += bf_hi(y0.z); aB6 += bf_lo(y0.w); aB7 += bf_hi(y0.w);
        aB0 += bf_lo(y1.x); aB1 += bf_hi(y1.x); aB2 += bf_lo(y1.y); aB3 += bf_hi(y1.y);
        aB4 += bf_lo(y1.z); aB5 += bf_hi(y1.z); aB6 += bf_lo(y1.w); aB7 += bf_hi(y1.w);
        aB0 += bf_lo(y2.x); aB1 += bf_hi(y2.x); aB2 += bf_lo(y2.y); aB3 += bf_hi(y2.y);
        aB4 += bf_lo(y2.z); aB5 += bf_hi(y2.z); aB6 += bf_lo(y2.w); aB7 += bf_hi(y2.w);
        aB0 += bf_lo(y3.x); aB1 += bf_hi(y3.x); aB2 += bf_lo(y3.y); aB3 += bf_hi(y3.y);
        aB4 += bf_lo(y3.z); aB5 += bf_hi(y3.z); aB6 += bf_lo(y3.w); aB7 += bf_hi(y3.w);
        aB0 += bf_lo(y4.x); aB1 += bf_hi(y4.x); aB2 += bf_lo(y4.y); aB3 += bf_hi(y4.y);
        aB4 += bf_lo(y4.z); aB5 += bf_hi(y4.z); aB6 += bf_lo(y4.w); aB7 += bf_hi(y4.w);
        aB0 += bf_lo(y5.x); aB1 += bf_hi(y5.x); aB2 += bf_lo(y5.y); aB3 += bf_hi(y5.y);
        aB4 += bf_lo(y5.z); aB5 += bf_hi(y5.z); aB6 += bf_lo(y5.w); aB7 += bf_hi(y5.w);
        aB0 += bf_lo(y6.x); aB1 += bf_hi(y6.x); aB2 += bf_lo(y6.y); aB3 += bf_hi(y6.y);
        aB4 += bf_lo(y6.z); aB5 += bf_hi(y6.z); aB6 += bf_lo(y6.w); aB7 += bf_hi(y6.w);
        aB0 += bf_lo(y7.x); aB1 += bf_hi(y7.x); aB2 += bf_lo(y7.y); aB3 += bf_hi(y7.y);
        aB4 += bf_lo(y7.z); aB5 += bf_hi(y7.z); aB6 += bf_lo(y7.w); aB7 += bf_hi(y7.w);
        eA += 8; eB += 8;
    }
    // drain A (batch 8 then scalar)
    for (; eA + 8 <= eA1v; eA += 8) {
        uint k0 = skey[eA + 0], k1 = skey[eA + 1], k2 = skey[eA + 2], k3 = skey[eA + 3];
        uint k4 = skey[eA + 4], k5 = skey[eA + 5], k6 = skey[eA + 6], k7 = skey[eA + 7];
        uint4 x0 = h128[(size_t)(k0 & 0xffffu) * 8 + p];
        uint4 x1 = h128[(size_t)(k1 & 0xffffu) * 8 + p];
        uint4 x2 = h128[(size_t)(k2 & 0xffffu) * 8 + p];
        uint4 x3 = h128[(size_t)(k3 & 0xffffu) * 8 + p];
        uint4 x4 = h128[(size_t)(k4 & 0xffffu) * 8 + p];
        uint4 x5 = h128[(size_t)(k5 & 0xffffu) * 8 + p];
        uint4 x6 = h128[(size_t)(k6 & 0xffffu) * 8 + p];
        uint4 x7 = h128[(size_t)(k7 & 0xffffu) * 8 + p];
        aA0 += bf_lo(x0.x); aA1 += bf_hi(x0.x); aA2 += bf_lo(x0.y); aA3 += bf_hi(x0.y);
        aA4 += bf_lo(x0.z); aA5 += bf_hi(x0.z); aA6 += bf_lo(x0.w); aA7 += bf_hi(x0.w);
        aA0 += bf_lo(x1.x); aA1 += bf_hi(x1.x); aA2 += bf_lo(x1.y); aA3 += bf_hi(x1.y);
        aA4 += bf_lo(x1.z); aA5 += bf_hi(x1.z); aA6 += bf_lo(x1.w); aA7 += bf_hi(x1.w);
        aA0 += bf_lo(x2.x); aA1 += bf_hi(x2.x); aA2 += bf_lo(x2.y); aA3 += bf_hi(x2.y);
        aA4 += bf_lo(x2.z); aA5 += bf_hi(x2.z); aA6 += bf_lo(x2.w); aA7 += bf_hi(x2.w);
        aA0 += bf_lo(x3.x); aA1 += bf_hi(x3.x); aA2 += bf_lo(x3.y); aA3 += bf_hi(x3.y);
        aA4 += bf_lo(x3.z); aA5 += bf_hi(x3.z); aA6 += bf_lo(x3.w); aA7 += bf_hi(x3.w);
        aA0 += bf_lo(x4.x); aA1 += bf_hi(x4.x); aA2 += bf_lo(x4.y); aA3 += bf_hi(x4.y);
        aA4 += bf_lo(x4.z); aA5 += bf_hi(x4.z); aA6 += bf_lo(x4.w); aA7 += bf_hi(x4.w);
        aA0 += bf_lo(x5.x); aA1 += bf_hi(x5.x); aA2 += bf_lo(x5.y); aA3 += bf_hi(x5.y);
        aA4 += bf_lo(x5.z); aA5 += bf_hi(x5.z); aA6 += bf_lo(x5.w); aA7 += bf_hi(x5.w);
        aA0 += bf_lo(x6.x); aA1 += bf_hi(x6.x); aA2 += bf_lo(x6.y); aA3 += bf_hi(x6.y);
        aA4 += bf_lo(x6.z); aA5 += bf_hi(x6.z); aA6 += bf_lo(x6.w); aA7 += bf_hi(x6.w);
        aA0 += bf_lo(x7.x); aA1 += bf_hi(x7.x); aA2 += bf_lo(x7.y); aA3 += bf_hi(x7.y);
        aA4 += bf_lo(x7.z); aA5 += bf_hi(x7.z); aA6 += bf_lo(x7.w); aA7 += bf_hi(x7.w);
    }
    for (; eA < eA1v; eA++) {
        uint4 x0 = h128[(size_t)(skey[eA] & 0xffffu) * 8 + p];
        aA0 += bf_lo(x0.x); aA1 += bf_hi(x0.x); aA2 += bf_lo(x0.y); aA3 += bf_hi(x0.y);
        aA4 += bf_lo(x0.z); aA5 += bf_hi(x0.z); aA6 += bf_lo(x0.w); aA7 += bf_hi(x0.w);
    }
    // drain B (batch 8 then scalar)
    for (; eB + 8 <= eB1v; eB += 8) {
        uint k0 = skey[eB + 0], k1 = skey[eB + 1], k2 = skey[eB + 2], k3 = skey[eB + 3];
        uint k4 = skey[eB + 4], k5 = skey[eB + 5], k6 = skey[eB + 6], k7 = skey[eB + 7];
        uint4 y0 = h128[(size_t)(k0 & 0xffffu) * 8 + p];
        uint4 y1 = h128[(size_t)(k1 & 0xffffu) * 8 + p];
        uint4 y2 = h128[(size_t)(k2 & 0xffffu) * 8 + p];
        uint4 y3 = h128[(size_t)(k3 & 0xffffu) * 8 + p];
        uint4 y4 = h128[(size_t)(k4 & 0xffffu) * 8 + p];
        uint4 y5 = h128[(size_t)(k5 & 0xffffu) * 8 + p];
        uint4 y6 = h128[(size_t)(k6 & 0xffffu) * 8 + p];
        uint4 y7 = h128[(size_t)(k7 & 0xffffu) * 8 + p];
        aB0 += bf_lo(y0.x); aB1 += bf_hi(y0.x); aB2 += bf_lo(y0.y); aB3 += bf_hi(y0.y);
        aB4 += bf_lo(y0.z); aB5 += bf_hi(y0.z); aB6 += bf_lo(y0.w); aB7 += bf_hi(y0.w);
        aB0 += bf_lo(y1.x); aB1 += bf_hi(y1.x); aB2 += bf_lo(y1.y); aB3 += bf_hi(y1.y);
        aB4 += bf_lo(y1.z); aB5 += bf_hi(y1.z); aB6 += bf_lo(y1.w); aB7 += bf_hi(y1.w);
        aB0 += bf_lo(y2.x); aB1 += bf_hi(y2.x); aB2 += bf_lo(y2.y); aB3 += bf_hi(y2.y);
        aB4 += bf_lo(y2.z); aB5 += bf_hi(y2.z); aB6 += bf_lo(y2.w); aB7 += bf_hi(y2.w);
        aB0 += bf_lo(y3.x); aB1 += bf_hi(y3.x); aB2 += bf_lo(y3.y); aB3 += bf_hi(y3.y);
        aB4 += bf_lo(y3.z); aB5 += bf_hi(y3.z); aB6 += bf_lo(y3.w); aB7 += bf_hi(y3.w);
        aB0 += bf_lo(y4.x); aB1 += bf_hi(y4.x); aB2 += bf_lo(y4.y); aB3 += bf_hi(y4.y);
        aB4 += bf_lo(y4.z); aB5 += bf_hi(y4.z); aB6 += bf_lo(y4.w); aB7 += bf_hi(y4.w);
        aB0 += bf_lo(y5.x); aB1 += bf_hi(y5.x); aB2 += bf_lo(y5.y); aB3 += bf_hi(y5.y);
        aB4 += bf_lo(y5.z); aB5 += bf_hi(y5.z); aB6 += bf_lo(y5.w); aB7 += bf_hi(y5.w);
        aB0 += bf_lo(y6.x); aB1 += bf_hi(y6.x); aB2 += bf_lo(y6.y); aB3 += bf_hi(y6.y);
        aB4 += bf_lo(y6.z); aB5 += bf_hi(y6.z); aB6 += bf_lo(y6.w); aB7 += bf_hi(y6.w);
        aB0 += bf_lo(y7.x); aB1 += bf_hi(y7.x); aB2 += bf_lo(y7.y); aB3 += bf_hi(y7.y);
        aB4 += bf_lo(y7.z); aB5 += bf_hi(y7.z); aB6 += bf_lo(y7.w); aB7 += bf_hi(y7.w);
    }
    for (; eB < eB1v; eB++) {
        uint4 y0 = h128[(size_t)(skey[eB] & 0xffffu) * 8 + p];
        aB0 += bf_lo(y0.x); aB1 += bf_hi(y0.x); aB2 += bf_lo(y0.y); aB3 += bf_hi(y0.y);
        aB4 += bf_lo(y0.z); aB5 += bf_hi(y0.z); aB6 += bf_lo(y0.w); aB7 += bf_hi(y0.w);
    }

    if (okA) {
        uint4 o;
        o.x = f2bf(aA0) | (f2bf(aA1) << 16);
        o.y = f2bf(aA2) | (f2bf(aA3) << 16);
        o.z = f2bf(aA4) | (f2bf(aA5) << 16);
        o.w = f2bf(aA6) | (f2bf(aA7) << 16);
        *(uint4*)&sX[rowA * LSTR + p * 8] = o;
    }
    if (okB) {
        uint4 o;
        o.x = f2bf(aB0) | (f2bf(aB1) << 16);
        o.y = f2bf(aB2) | (f2bf(aB3) << 16);
        o.z = f2bf(aB4) | (f2bf(aB5) << 16);
        o.w = f2bf(aB6) | (f2bf(aB7) << 16);
        *(uint4*)&sX[rowB * LSTR + p * 8] = o;
    }
    // no barrier: rows m0..m0+15 are wave-private from here on

    // ---- MFMA MLP (layouts verified learn_hip m89/m91)
    int mc = lane & 15;
    int quad = lane >> 4;

    bf16x8 xa0 = *(const bf16x8*)&sX[(m0 + mc) * LSTR + quad * 8];
    bf16x8 xa1 = *(const bf16x8*)&sX[(m0 + mc) * LSTR + 32 + quad * 8];
    ushort hreg[16];
#pragma unroll
    for (int c = 0; c < 4; c++) {
        bf16x8 b0 = *(const bf16x8*)&sW1[(c * 16 + mc) * LSTR + quad * 8];
        bf16x8 b1 = *(const bf16x8*)&sW1[(c * 16 + mc) * LSTR + 32 + quad * 8];
        f32x4 acc = {0.f, 0.f, 0.f, 0.f};
        acc = __builtin_amdgcn_mfma_f32_16x16x32_bf16(xa0, b0, acc, 0, 0, 0);
        acc = __builtin_amdgcn_mfma_f32_16x16x32_bf16(xa1, b1, acc, 0, 0, 0);
        int col = c * 16 + mc;
        float bias = sba[col];
#pragma unroll
        for (int r = 0; r < 4; r++)
            hreg[c * 4 + r] = (ushort)f2bf(fmaxf(acc[r] + bias, 0.f));
    }
#pragma unroll
    for (int c = 0; c < 4; c++) {
        int col = c * 16 + mc;
#pragma unroll
        for (int r = 0; r < 4; r++)
            sX[(m0 + quad * 4 + r) * LSTR + col] = hreg[c * 4 + r];
    }

    bf16x8 ha0 = *(const bf16x8*)&sX[(m0 + mc) * LSTR + quad * 8];
    bf16x8 ha1 = *(const bf16x8*)&sX[(m0 + mc) * LSTR + 32 + quad * 8];
#pragma unroll
    for (int c = 0; c < 4; c++) {
        bf16x8 b0 = *(const bf16x8*)&sW2[(c * 16 + mc) * LSTR + quad * 8];
        bf16x8 b1 = *(const bf16x8*)&sW2[(c * 16 + mc) * LSTR + 32 + quad * 8];
        f32x4 acc = {0.f, 0.f, 0.f, 0.f};
        acc = __builtin_amdgcn_mfma_f32_16x16x32_bf16(ha0, b0, acc, 0, 0, 0);
        acc = __builtin_amdgcn_mfma_f32_16x16x32_bf16(ha1, b1, acc, 0, 0, 0);
        int col = c * 16 + mc;
        float bias = sbb[col];
#pragma unroll
        for (int r = 0; r < 4; r++)
            hreg[c * 4 + r] = (ushort)f2bf(acc[r] + bias);
    }
#pragma unroll
    for (int c = 0; c < 4; c++) {
        int col = c * 16 + mc;
#pragma unroll
        for (int r = 0; r < 4; r++)
            sX[(m0 + quad * 4 + r) * LSTR + col] = hreg[c * 4 + r];
    }

    // output: wave-private rows, 2 x uint4 per lane
#pragma unroll
    for (int i = 0; i < 2; i++) {
        int idx = i * 64 + lane;          // 0..127
        int row16 = idx >> 3, q = idx & 7;
        int row = m0 + row16;
        int gr = node0 + row;
        if (gr < n) out128[(size_t)gr * 8 + q] = *(const uint4*)&sX[row * LSTR + q * 8];
    }
}

// ---------------- mean pool (2 stages, bf16 input) + final linear ----------------

__global__ __launch_bounds__(256) void colsum_part_kernel(const uint* __restrict__ h32,
                                                          float* __restrict__ part, int n) {
    __shared__ float red[8][64];
    int t = threadIdx.x;
    int g = t >> 5, p = t & 31;
    float a0 = 0.f, a1 = 0.f;
    for (int i = blockIdx.x * 8 + g; i < n; i += gridDim.x * 8) {
        uint u = h32[(size_t)i * 32 + p];
        a0 += bf_lo(u);
        a1 += bf_hi(u);
    }
    red[g][2 * p]     = a0;
    red[g][2 * p + 1] = a1;
    __syncthreads();
    if (t < 64) {
        float s = 0.f;
        for (int gg = 0; gg < 8; gg++) s += red[gg][t];
        part[blockIdx.x * 64 + t] = s;
    }
}

__global__ __launch_bounds__(64) void final_kernel(const float* __restrict__ part,
                                                   const float* __restrict__ Wout,
                                                   const float* __restrict__ bout,
                                                   float* __restrict__ out, int nparts) {
    __shared__ float cs[64];
    int t = threadIdx.x;
    float s = 0.f;
    for (int b = 0; b < nparts; b++) s += part[b * 64 + t];
    cs[t] = s * (1.0f / (float)NNODES);
    __syncthreads();
    if (t < DOUT) {
        float o = bout[t];
        for (int d = 0; d < DDIM; d++) o += cs[d] * Wout[d * DOUT + t];
        out[t] = o;
    }
}

// ---------------- launch ----------------

extern "C" void kernel_launch(void* const* d_in, const int* in_sizes, int n_in,
                              void* d_out, int out_size, void* d_ws, size_t ws_size,
                              hipStream_t stream) {
    const float* features = (const float*)d_in[0];
    const int*   src      = (const int*)d_in[1];
    const int*   dst      = (const int*)d_in[2];
    const float* W0a = (const float*)d_in[3];  const float* b0a = (const float*)d_in[4];
    const float* W0b = (const float*)d_in[5];  const float* b0b = (const float*)d_in[6];
    const float* W1a = (const float*)d_in[7];  const float* b1a = (const float*)d_in[8];
    const float* W1b = (const float*)d_in[9];  const float* b1b = (const float*)d_in[10];
    const float* W2a = (const float*)d_in[11]; const float* b2a = (const float*)d_in[12];
    const float* W2b = (const float*)d_in[13]; const float* b2b = (const float*)d_in[14];
    const float* Wout = (const float*)d_in[15]; const float* bout = (const float*)d_in[16];
    float* out = (float*)d_out;

    // workspace layout (16B-aligned segments)
    int* gh     = (int*)d_ws;              // [38416]
    int* offraw = gh + 38416;              // [38416]
    int* tot    = offraw + 38416;          // [256]
    int* bbase  = tot + 256;               // [197] -> pad 208
    int* rowptr = bbase + 208;             // [50001] -> pad 50016
    uint* keybuf = (uint*)(rowptr + 50016);  // [800000] (final sorted edge list)
    uint* buf2   = keybuf + 800000;          // [800000] (pass-1 partitioned)
    uint* hb0    = buf2 + 800000;            // bf16 h ping [50000*32]
    uint* hb1    = hb0 + NNODES * 32;        // bf16 h pong
    float* part  = (float*)(hb1 + NNODES * 32); // [128*64]

    // edge sort (+ feature cvt fused into S1's tail blocks)
    sort_hist_cvt_kernel<<<NB1 + NBCVT, 256, 0, stream>>>(src, dst, keybuf, gh,
                                                          (const float2*)features, hb0, NEDGES);
    sort_offsets_a_kernel<<<NBUCK, 256, 0, stream>>>(gh, offraw, tot);
    sort_offsets_b_kernel<<<1, 256, 0, stream>>>(tot, bbase);
    sort_scatter1_kernel<<<NB1, 256, 0, stream>>>(keybuf, offraw, bbase, buf2, NEDGES);
    sort_bucket_kernel<<<NBUCK, 256, 0, stream>>>(buf2, bbase, rowptr, keybuf);

    // 3 fused GIN layers
    gin_layer_kernel<<<NB64, 256, 0, stream>>>((const uint4*)hb0, rowptr, keybuf,
                                               W0a, b0a, W0b, b0b, (uint4*)hb1, NNODES);
    gin_layer_kernel<<<NB64, 256, 0, stream>>>((const uint4*)hb1, rowptr, keybuf,
                                               W1a, b1a, W1b, b1b, (uint4*)hb0, NNODES);
    gin_layer_kernel<<<NB64, 256, 0, stream>>>((const uint4*)hb0, rowptr, keybuf,
                                               W2a, b2a, W2b, b2b, (uint4*)hb1, NNODES);

    // mean pool + final linear
    colsum_part_kernel<<<128, 256, 0, stream>>>(hb1, part, NNODES);
    final_kernel<<<1, 64, 0, stream>>>(part, Wout, bout, out, 128);
}

// Round 11
// 254.041 us; speedup vs baseline: 1.0433x; 1.0433x over previous
//
#include <hip/hip_runtime.h>
#include <hip/hip_bf16.h>

// GIN: 3x [agg = segment_sum(h[src], dst); r = h + agg; h = relu(r@Wa+ba)@Wb+bb]
// then mean over nodes @ Wout + bout -> [1,16]
//
// R11 = revert to R9 (measured optimum, 255us). R10's dual-row interleaved
// gather regressed (+10us): mean degree 16 -> joint loop ran ~1 iter before
// sequential drains; doubled hot-loop VGPR pressure for no MLW gain.
// R9 structure: 8-lane x uint4 gather (16B/lane, batch-8 independent loads,
// fp32 register acc), single-barrier gin kernel (gather/MFMA/hidden/output all
// wave-private after weight staging), no-global-atomic 2-pass MSD edge sort
// with parallel scans, 2-stage mean pool.

#define NNODES 50000
#define NEDGES 800000
#define DDIM   64
#define DOUT   16

#define CHUNK  4096
#define NB1    196           // ceil(800000/4096)
#define NBUCK  196           // ceil(50000/256), bucket = dst>>8
#define NBCVT  6250          // cvt blocks: 1.6M float2 / 256
#define NB64   782           // ceil(50000/64), fused-layer blocks

typedef unsigned int uint;
typedef unsigned short ushort;
typedef __attribute__((ext_vector_type(8))) short bf16x8;
typedef __attribute__((ext_vector_type(4))) float f32x4;

#define LSTR 72   // LDS row stride in ushorts (144B rows, 16B-aligned)

// fp32 -> bf16 RNE (bit trick)
static __device__ __forceinline__ uint f2bf(float f) {
    uint u = __float_as_uint(f);
    return (u + 0x7fffu + ((u >> 16) & 1u)) >> 16;
}
static __device__ __forceinline__ float bf_lo(uint u) { return __uint_as_float(u << 16); }
static __device__ __forceinline__ float bf_hi(uint u) { return __uint_as_float(u & 0xffff0000u); }

// ---------------- S1: pack keys + per-block bucket hist; tail blocks do cvt ----------------

__global__ __launch_bounds__(256) void sort_hist_cvt_kernel(const int* __restrict__ src,
                                                            const int* __restrict__ dst,
                                                            uint* __restrict__ key,
                                                            int* __restrict__ gh,
                                                            const float2* __restrict__ fin,
                                                            uint* __restrict__ hb, int n) {
    __shared__ int h[NBUCK];
    int blk = blockIdx.x;
    if (blk >= NB1) {
        int i = (blk - NB1) * 256 + threadIdx.x;
        if (i < NNODES * 32) {
            float2 v = fin[i];
            hb[i] = f2bf(v.x) | (f2bf(v.y) << 16);
        }
        return;
    }
    for (int i = threadIdx.x; i < NBUCK; i += 256) h[i] = 0;
    __syncthreads();
    int base = blk * CHUNK;
    int end = base + CHUNK < n ? base + CHUNK : n;
    for (int i = base + threadIdx.x; i < end; i += 256) {
        int d = dst[i];
        key[i] = ((uint)d << 16) | (uint)src[i];
        atomicAdd(&h[d >> 8], 1);
    }
    __syncthreads();
    for (int i = threadIdx.x; i < NBUCK; i += 256) gh[blk * NBUCK + i] = h[i];
}

// ---------------- S2a: per-bucket scan over the 196 chunk counts ----------------

__global__ __launch_bounds__(256) void sort_offsets_a_kernel(const int* __restrict__ gh,
                                                             int* __restrict__ offraw,
                                                             int* __restrict__ tot) {
    __shared__ int s[256];
    int b = blockIdx.x;
    int i = threadIdx.x;
    int v = (i < NB1) ? gh[i * NBUCK + b] : 0;
    s[i] = v;
    __syncthreads();
    for (int off = 1; off < 256; off <<= 1) {
        int add = (i >= off) ? s[i - off] : 0;
        __syncthreads();
        s[i] += add;
        __syncthreads();
    }
    if (i < NB1) offraw[i * NBUCK + b] = s[i] - v;   // exclusive within bucket
    if (i == 255) tot[b] = s[255];
}

// ---------------- S2b: scan bucket totals -> bucket bases ----------------

__global__ __launch_bounds__(256) void sort_offsets_b_kernel(const int* __restrict__ tot,
                                                             int* __restrict__ bbase) {
    __shared__ int s[256];
    int i = threadIdx.x;
    int v = (i < NBUCK) ? tot[i] : 0;
    s[i] = v;
    __syncthreads();
    for (int off = 1; off < 256; off <<= 1) {
        int add = (i >= off) ? s[i - off] : 0;
        __syncthreads();
        s[i] += add;
        __syncthreads();
    }
    if (i < NBUCK) bbase[i] = s[i] - v;   // exclusive
    if (i == 0) bbase[NBUCK] = NEDGES;
}

// ---------------- S3: partition into coarse buckets (block-private runs) ----------------

__global__ __launch_bounds__(256) void sort_scatter1_kernel(const uint* __restrict__ key,
                                                            const int* __restrict__ offraw,
                                                            const int* __restrict__ bbase,
                                                            uint* __restrict__ out, int n) {
    __shared__ int cur[NBUCK];
    int blk = blockIdx.x;
    for (int i = threadIdx.x; i < NBUCK; i += 256)
        cur[i] = bbase[i] + offraw[blk * NBUCK + i];
    __syncthreads();
    int base = blk * CHUNK;
    int end = base + CHUNK < n ? base + CHUNK : n;
    for (int i = base + threadIdx.x; i < end; i += 256) {
        uint k = key[i];
        int pos = atomicAdd(&cur[k >> 24], 1);   // k>>24 == dst>>8
        out[pos] = k;
    }
}

// ---------------- S4: per-bucket counting sort by dst&255; emits rowptr ----------------

__global__ __launch_bounds__(256) void sort_bucket_kernel(const uint* __restrict__ in,
                                                          const int* __restrict__ bbase,
                                                          int* __restrict__ rowptr,
                                                          uint* __restrict__ out) {
    __shared__ int h[256];
    __shared__ int cur[256];
    int b = blockIdx.x;
    int t = threadIdx.x;
    int lo = bbase[b], hi = bbase[b + 1];
    h[t] = 0;
    __syncthreads();
    for (int i = lo + t; i < hi; i += 256)
        atomicAdd(&h[(in[i] >> 16) & 255], 1);
    __syncthreads();
    if (t == 0) {
        int run = lo;
        for (int i = 0; i < 256; i++) { cur[i] = run; run += h[i]; }
    }
    __syncthreads();
    int node = (b << 8) + t;
    if (node < NNODES) rowptr[node] = cur[t];
    if (b == NBUCK - 1 && t == 0) rowptr[NNODES] = NEDGES;
    __syncthreads();   // rowptr reads of cur[] before scatter mutates it
    for (int i = lo + t; i < hi; i += 256) {
        uint k = in[i];
        int pos = atomicAdd(&cur[(k >> 16) & 255], 1);
        out[pos] = k;
    }
}

// ---------------- fused GIN layer: gather-agg + relu(X@Wa+ba)@Wb+bb ----------------
// 64 nodes/block, 4 waves; wave w owns rows 16w..16w+15 end-to-end (gather,
// MFMA, hidden, output) -> single barrier after weight staging.
// Gather: group g (8 lanes, p=lane&7, uint4 = dims 8p..8p+7) handles rows
// m0+g and m0+8+g; batch-8 independent 16B gathers, fp32 register acc.

__global__ __launch_bounds__(256) void gin_layer_kernel(const uint4* __restrict__ h128,
                                                        const int* __restrict__ rowptr,
                                                        const uint* __restrict__ skey,
                                                        const float* __restrict__ Wa,
                                                        const float* __restrict__ ba,
                                                        const float* __restrict__ Wb,
                                                        const float* __restrict__ bb,
                                                        uint4* __restrict__ out128, int n) {
    __shared__ ushort sW1[64 * LSTR];   // Wa^T: [n][k]
    __shared__ ushort sW2[64 * LSTR];   // Wb^T: [n][k]
    __shared__ ushort sX[64 * LSTR];    // r tile -> hidden tile -> output staging
    __shared__ float sba[64], sbb[64];

    int t = threadIdx.x;
    for (int i = t; i < 4096; i += 256) {
        int k = i >> 6, nn = i & 63;
        sW1[nn * LSTR + k] = (ushort)f2bf(Wa[i]);
        sW2[nn * LSTR + k] = (ushort)f2bf(Wb[i]);
    }
    if (t < 64) { sba[t] = ba[t]; sbb[t] = bb[t]; }
    __syncthreads();   // the only barrier: weights visible to all waves

    int node0 = blockIdx.x * 64;
    int lane = t & 63;
    int w = t >> 6;
    int m0 = w * 16;
    int g = lane >> 3;       // group 0..7
    int p = lane & 7;        // uint4 index (dims 8p..8p+7)

#pragma unroll
    for (int s = 0; s < 2; s++) {
        int row = m0 + 8 * s + g;
        int v = node0 + row;
        if (v < n) {
            uint4 su = h128[(size_t)v * 8 + p];
            float a0 = bf_lo(su.x), a1 = bf_hi(su.x), a2 = bf_lo(su.y), a3 = bf_hi(su.y);
            float a4 = bf_lo(su.z), a5 = bf_hi(su.z), a6 = bf_lo(su.w), a7 = bf_hi(su.w);
            int e = rowptr[v], e1 = rowptr[v + 1];
            for (; e + 8 <= e1; e += 8) {
                uint k0 = skey[e + 0], k1 = skey[e + 1], k2 = skey[e + 2], k3 = skey[e + 3];
                uint k4 = skey[e + 4], k5 = skey[e + 5], k6 = skey[e + 6], k7 = skey[e + 7];
                uint4 v0 = h128[(size_t)(k0 & 0xffffu) * 8 + p];
                uint4 v1 = h128[(size_t)(k1 & 0xffffu) * 8 + p];
                uint4 v2 = h128[(size_t)(k2 & 0xffffu) * 8 + p];
                uint4 v3 = h128[(size_t)(k3 & 0xffffu) * 8 + p];
                uint4 v4 = h128[(size_t)(k4 & 0xffffu) * 8 + p];
                uint4 v5 = h128[(size_t)(k5 & 0xffffu) * 8 + p];
                uint4 v6 = h128[(size_t)(k6 & 0xffffu) * 8 + p];
                uint4 v7 = h128[(size_t)(k7 & 0xffffu) * 8 + p];
                a0 += bf_lo(v0.x); a1 += bf_hi(v0.x); a2 += bf_lo(v0.y); a3 += bf_hi(v0.y);
                a4 += bf_lo(v0.z); a5 += bf_hi(v0.z); a6 += bf_lo(v0.w); a7 += bf_hi(v0.w);
                a0 += bf_lo(v1.x); a1 += bf_hi(v1.x); a2 += bf_lo(v1.y); a3 += bf_hi(v1.y);
                a4 += bf_lo(v1.z); a5 += bf_hi(v1.z); a6 += bf_lo(v1.w); a7 += bf_hi(v1.w);
                a0 += bf_lo(v2.x); a1 += bf_hi(v2.x); a2 += bf_lo(v2.y); a3 += bf_hi(v2.y);
                a4 += bf_lo(v2.z); a5 += bf_hi(v2.z); a6 += bf_lo(v2.w); a7 += bf_hi(v2.w);
                a0 += bf_lo(v3.x); a1 += bf_hi(v3.x); a2 += bf_lo(v3.y); a3 += bf_hi(v3.y);
                a4 += bf_lo(v3.z); a5 += bf_hi(v3.z); a6 += bf_lo(v3.w); a7 += bf_hi(v3.w);
                a0 += bf_lo(v4.x); a1 += bf_hi(v4.x); a2 += bf_lo(v4.y); a3 += bf_hi(v4.y);
                a4 += bf_lo(v4.z); a5 += bf_hi(v4.z); a6 += bf_lo(v4.w); a7 += bf_hi(v4.w);
                a0 += bf_lo(v5.x); a1 += bf_hi(v5.x); a2 += bf_lo(v5.y); a3 += bf_hi(v5.y);
                a4 += bf_lo(v5.z); a5 += bf_hi(v5.z); a6 += bf_lo(v5.w); a7 += bf_hi(v5.w);
                a0 += bf_lo(v6.x); a1 += bf_hi(v6.x); a2 += bf_lo(v6.y); a3 += bf_hi(v6.y);
                a4 += bf_lo(v6.z); a5 += bf_hi(v6.z); a6 += bf_lo(v6.w); a7 += bf_hi(v6.w);
                a0 += bf_lo(v7.x); a1 += bf_hi(v7.x); a2 += bf_lo(v7.y); a3 += bf_hi(v7.y);
                a4 += bf_lo(v7.z); a5 += bf_hi(v7.z); a6 += bf_lo(v7.w); a7 += bf_hi(v7.w);
            }
            for (; e < e1; e++) {
                uint4 v0 = h128[(size_t)(skey[e] & 0xffffu) * 8 + p];
                a0 += bf_lo(v0.x); a1 += bf_hi(v0.x); a2 += bf_lo(v0.y); a3 += bf_hi(v0.y);
                a4 += bf_lo(v0.z); a5 += bf_hi(v0.z); a6 += bf_lo(v0.w); a7 += bf_hi(v0.w);
            }
            uint4 o;
            o.x = f2bf(a0) | (f2bf(a1) << 16);
            o.y = f2bf(a2) | (f2bf(a3) << 16);
            o.z = f2bf(a4) | (f2bf(a5) << 16);
            o.w = f2bf(a6) | (f2bf(a7) << 16);
            *(uint4*)&sX[row * LSTR + p * 8] = o;
        }
    }
    // no barrier: rows m0..m0+15 are wave-private from here on

    // ---- MFMA MLP (layouts verified learn_hip m89/m91)
    int mc = lane & 15;
    int quad = lane >> 4;

    bf16x8 xa0 = *(const bf16x8*)&sX[(m0 + mc) * LSTR + quad * 8];
    bf16x8 xa1 = *(const bf16x8*)&sX[(m0 + mc) * LSTR + 32 + quad * 8];
    ushort hreg[16];
#pragma unroll
    for (int c = 0; c < 4; c++) {
        bf16x8 b0 = *(const bf16x8*)&sW1[(c * 16 + mc) * LSTR + quad * 8];
        bf16x8 b1 = *(const bf16x8*)&sW1[(c * 16 + mc) * LSTR + 32 + quad * 8];
        f32x4 acc = {0.f, 0.f, 0.f, 0.f};
        acc = __builtin_amdgcn_mfma_f32_16x16x32_bf16(xa0, b0, acc, 0, 0, 0);
        acc = __builtin_amdgcn_mfma_f32_16x16x32_bf16(xa1, b1, acc, 0, 0, 0);
        int col = c * 16 + mc;
        float bias = sba[col];
#pragma unroll
        for (int r = 0; r < 4; r++)
            hreg[c * 4 + r] = (ushort)f2bf(fmaxf(acc[r] + bias, 0.f));
    }
#pragma unroll
    for (int c = 0; c < 4; c++) {
        int col = c * 16 + mc;
#pragma unroll
        for (int r = 0; r < 4; r++)
            sX[(m0 + quad * 4 + r) * LSTR + col] = hreg[c * 4 + r];
    }

    bf16x8 ha0 = *(const bf16x8*)&sX[(m0 + mc) * LSTR + quad * 8];
    bf16x8 ha1 = *(const bf16x8*)&sX[(m0 + mc) * LSTR + 32 + quad * 8];
#pragma unroll
    for (int c = 0; c < 4; c++) {
        bf16x8 b0 = *(const bf16x8*)&sW2[(c * 16 + mc) * LSTR + quad * 8];
        bf16x8 b1 = *(const bf16x8*)&sW2[(c * 16 + mc) * LSTR + 32 + quad * 8];
        f32x4 acc = {0.f, 0.f, 0.f, 0.f};
        acc = __builtin_amdgcn_mfma_f32_16x16x32_bf16(ha0, b0, acc, 0, 0, 0);
        acc = __builtin_amdgcn_mfma_f32_16x16x32_bf16(ha1, b1, acc, 0, 0, 0);
        int col = c * 16 + mc;
        float bias = sbb[col];
#pragma unroll
        for (int r = 0; r < 4; r++)
            hreg[c * 4 + r] = (ushort)f2bf(acc[r] + bias);
    }
#pragma unroll
    for (int c = 0; c < 4; c++) {
        int col = c * 16 + mc;
#pragma unroll
        for (int r = 0; r < 4; r++)
            sX[(m0 + quad * 4 + r) * LSTR + col] = hreg[c * 4 + r];
    }

    // output: wave-private rows, 2 x uint4 per lane
#pragma unroll
    for (int i = 0; i < 2; i++) {
        int idx = i * 64 + lane;          // 0..127
        int row16 = idx >> 3, q = idx & 7;
        int row = m0 + row16;
        int gr = node0 + row;
        if (gr < n) out128[(size_t)gr * 8 + q] = *(const uint4*)&sX[row * LSTR + q * 8];
    }
}

// ---------------- mean pool (2 stages, bf16 input) + final linear ----------------

__global__ __launch_bounds__(256) void colsum_part_kernel(const uint* __restrict__ h32,
                                                          float* __restrict__ part, int n) {
    __shared__ float red[8][64];
    int t = threadIdx.x;
    int g = t >> 5, p = t & 31;
    float a0 = 0.f, a1 = 0.f;
    for (int i = blockIdx.x * 8 + g; i < n; i += gridDim.x * 8) {
        uint u = h32[(size_t)i * 32 + p];
        a0 += bf_lo(u);
        a1 += bf_hi(u);
    }
    red[g][2 * p]     = a0;
    red[g][2 * p + 1] = a1;
    __syncthreads();
    if (t < 64) {
        float s = 0.f;
        for (int gg = 0; gg < 8; gg++) s += red[gg][t];
        part[blockIdx.x * 64 + t] = s;
    }
}

__global__ __launch_bounds__(64) void final_kernel(const float* __restrict__ part,
                                                   const float* __restrict__ Wout,
                                                   const float* __restrict__ bout,
                                                   float* __restrict__ out, int nparts) {
    __shared__ float cs[64];
    int t = threadIdx.x;
    float s = 0.f;
    for (int b = 0; b < nparts; b++) s += part[b * 64 + t];
    cs[t] = s * (1.0f / (float)NNODES);
    __syncthreads();
    if (t < DOUT) {
        float o = bout[t];
        for (int d = 0; d < DDIM; d++) o += cs[d] * Wout[d * DOUT + t];
        out[t] = o;
    }
}

// ---------------- launch ----------------

extern "C" void kernel_launch(void* const* d_in, const int* in_sizes, int n_in,
                              void* d_out, int out_size, void* d_ws, size_t ws_size,
                              hipStream_t stream) {
    const float* features = (const float*)d_in[0];
    const int*   src      = (const int*)d_in[1];
    const int*   dst      = (const int*)d_in[2];
    const float* W0a = (const float*)d_in[3];  const float* b0a = (const float*)d_in[4];
    const float* W0b = (const float*)d_in[5];  const float* b0b = (const float*)d_in[6];
    const float* W1a = (const float*)d_in[7];  const float* b1a = (const float*)d_in[8];
    const float* W1b = (const float*)d_in[9];  const float* b1b = (const float*)d_in[10];
    const float* W2a = (const float*)d_in[11]; const float* b2a = (const float*)d_in[12];
    const float* W2b = (const float*)d_in[13]; const float* b2b = (const float*)d_in[14];
    const float* Wout = (const float*)d_in[15]; const float* bout = (const float*)d_in[16];
    float* out = (float*)d_out;

    // workspace layout (16B-aligned segments)
    int* gh     = (int*)d_ws;              // [38416]
    int* offraw = gh + 38416;              // [38416]
    int* tot    = offraw + 38416;          // [256]
    int* bbase  = tot + 256;               // [197] -> pad 208
    int* rowptr = bbase + 208;             // [50001] -> pad 50016
    uint* keybuf = (uint*)(rowptr + 50016);  // [800000] (final sorted edge list)
    uint* buf2   = keybuf + 800000;          // [800000] (pass-1 partitioned)
    uint* hb0    = buf2 + 800000;            // bf16 h ping [50000*32]
    uint* hb1    = hb0 + NNODES * 32;        // bf16 h pong
    float* part  = (float*)(hb1 + NNODES * 32); // [128*64]

    // edge sort (+ feature cvt fused into S1's tail blocks)
    sort_hist_cvt_kernel<<<NB1 + NBCVT, 256, 0, stream>>>(src, dst, keybuf, gh,
                                                          (const float2*)features, hb0, NEDGES);
    sort_offsets_a_kernel<<<NBUCK, 256, 0, stream>>>(gh, offraw, tot);
    sort_offsets_b_kernel<<<1, 256, 0, stream>>>(tot, bbase);
    sort_scatter1_kernel<<<NB1, 256, 0, stream>>>(keybuf, offraw, bbase, buf2, NEDGES);
    sort_bucket_kernel<<<NBUCK, 256, 0, stream>>>(buf2, bbase, rowptr, keybuf);

    // 3 fused GIN layers
    gin_layer_kernel<<<NB64, 256, 0, stream>>>((const uint4*)hb0, rowptr, keybuf,
                                               W0a, b0a, W0b, b0b, (uint4*)hb1, NNODES);
    gin_layer_kernel<<<NB64, 256, 0, stream>>>((const uint4*)hb1, rowptr, keybuf,
                                               W1a, b1a, W1b, b1b, (uint4*)hb0, NNODES);
    gin_layer_kernel<<<NB64, 256, 0, stream>>>((const uint4*)hb0, rowptr, keybuf,
                                               W2a, b2a, W2b, b2b, (uint4*)hb1, NNODES);

    // mean pool + final linear
    colsum_part_kernel<<<128, 256, 0, stream>>>(hb1, part, NNODES);
    final_kernel<<<1, 64, 0, stream>>>(part, Wout, bout, out, 128);
}